// Round 1
// baseline (178.130 us; speedup 1.0000x reference)
//
#include <hip/hip_runtime.h>
#include <math.h>

#define EPSF 1e-15f
#define MAX_TANH_F (1.0f - 1e-5f)

#define KDIM 512
#define NOUT 256
#define TM   16
#define LDF  516   // padded leading dim (floats), keeps float4 alignment, rotates banks

__device__ __forceinline__ float wave_reduce_sum(float v) {
    // full 64-lane butterfly
    v += __shfl_xor(v, 32);
    v += __shfl_xor(v, 16);
    v += __shfl_xor(v, 8);
    v += __shfl_xor(v, 4);
    v += __shfl_xor(v, 2);
    v += __shfl_xor(v, 1);
    return v;
}

__device__ __forceinline__ float artanh_clip(float x) {
    x = fminf(fmaxf(x, -MAX_TANH_F), MAX_TANH_F);
    return atanhf(x);
}

// K1: h = mobius_matvec(feat*scale, W); also store hnorm2 = ||h||^2 per row.
// Block: 256 threads, handles TM=16 rows. Each thread owns one output column.
__global__ __launch_bounds__(256) void matvec_mobius_kernel(
    const float* __restrict__ feat, const float* __restrict__ W,
    float* __restrict__ h, float* __restrict__ hnorm2,
    float scale, int N)
{
    __shared__ float sfeat[TM][LDF];
    __shared__ float sred[4][TM];
    __shared__ float sfac[TM];
    __shared__ float sxn2[TM];

    const int tid  = threadIdx.x;
    const int base = blockIdx.x * TM;

    // stage 16x512 floats (scaled) into LDS, float4 coalesced
    {
        const float4* fin = (const float4*)feat;
        #pragma unroll
        for (int i = 0; i < (TM * KDIM / 4) / 256; ++i) {  // 8 iters
            int g   = tid + i * 256;            // float4 index within tile
            int r   = g >> 7;                   // /(KDIM/4)
            int c4  = g & 127;
            int row = base + r;
            float4 v = make_float4(0.f, 0.f, 0.f, 0.f);
            if (row < N) v = fin[(size_t)row * (KDIM / 4) + c4];
            *(float4*)&sfeat[r][c4 * 4] =
                make_float4(v.x * scale, v.y * scale, v.z * scale, v.w * scale);
        }
    }
    __syncthreads();

    // x_norm^2 per row (on scaled feat): 16 lanes per row
    {
        int r = tid >> 4;
        int l = tid & 15;
        float p = 0.f;
        #pragma unroll
        for (int j = 0; j < KDIM / 16; ++j) {
            float v = sfeat[r][l + 16 * j];
            p = fmaf(v, v, p);
        }
        p += __shfl_xor(p, 8);
        p += __shfl_xor(p, 4);
        p += __shfl_xor(p, 2);
        p += __shfl_xor(p, 1);
        if (l == 0) sxn2[r] = p;
    }

    // GEMM: acc[r] = dot(sfeat[r][:], W[:, col])
    float acc[TM];
    #pragma unroll
    for (int r = 0; r < TM; ++r) acc[r] = 0.f;

    const int col = tid;
    for (int k = 0; k < KDIM; k += 4) {
        float w0 = W[(size_t)(k + 0) * NOUT + col];
        float w1 = W[(size_t)(k + 1) * NOUT + col];
        float w2 = W[(size_t)(k + 2) * NOUT + col];
        float w3 = W[(size_t)(k + 3) * NOUT + col];
        #pragma unroll
        for (int r = 0; r < TM; ++r) {
            float4 f4 = *(const float4*)&sfeat[r][k];
            acc[r] = fmaf(f4.x, w0, acc[r]);
            acc[r] = fmaf(f4.y, w1, acc[r]);
            acc[r] = fmaf(f4.z, w2, acc[r]);
            acc[r] = fmaf(f4.w, w3, acc[r]);
        }
    }

    // mx_norm^2 per row: wave reduce then cross-wave via LDS
    const int wave = tid >> 6;
    const int lane = tid & 63;
    #pragma unroll
    for (int r = 0; r < TM; ++r) {
        float v = wave_reduce_sum(acc[r] * acc[r]);
        if (lane == 0) sred[wave][r] = v;
    }
    __syncthreads();
    if (tid < TM) {
        int r = tid;
        float mx2 = sred[0][r] + sred[1][r] + sred[2][r] + sred[3][r];
        float mxn = fmaxf(sqrtf(mx2), EPSF);
        float xn  = fmaxf(sqrtf(sxn2[r]), EPSF);
        float t   = tanhf(mxn / xn * artanh_clip(xn));
        float fac = t / mxn;
        if (mxn <= 1e-10f) { fac = 0.f; t = 0.f; }
        sfac[r] = fac;
        if (base + r < N) hnorm2[base + r] = t * t;
    }
    __syncthreads();

    #pragma unroll
    for (int r = 0; r < TM; ++r) {
        if (base + r < N)
            h[(size_t)(base + r) * NOUT + col] = sfac[r] * acc[r];
    }
}

// K2: sequential mobius_add scan over h[src[n][0..15]], then *scale,
// mobius_add bias, expmap0(relu(logmap0(.))). One wave per output row.
__global__ __launch_bounds__(256) void aggregate_kernel(
    const float* __restrict__ h, const float* __restrict__ hnorm2,
    const int* __restrict__ src, const float* __restrict__ bias,
    float* __restrict__ out, float scale, int N, int DEG)
{
    const int wave = threadIdx.x >> 6;
    const int lane = threadIdx.x & 63;
    const int n = blockIdx.x * 4 + wave;
    if (n >= N) return;
    const int* s = src + (size_t)n * DEG;

    int s0 = s[0];
    float4 c = *(const float4*)&h[(size_t)s0 * NOUT + lane * 4];
    float c2 = hnorm2[s0];

    for (int j = 1; j < DEG; ++j) {
        int sj = s[j];
        float4 y = *(const float4*)&h[(size_t)sj * NOUT + lane * 4];
        float y2 = hnorm2[sj];
        float xyp = c.x * y.x + c.y * y.y + c.z * y.z + c.w * y.w;
        float xy = wave_reduce_sum(xyp);
        float A = 1.f + 2.f * xy + y2;
        float B = 1.f - c2;
        float den = fmaxf(1.f + 2.f * xy + c2 * y2, EPSF);
        float inv = 1.f / den;
        c.x = (A * c.x + B * y.x) * inv;
        c.y = (A * c.y + B * y.y) * inv;
        c.z = (A * c.z + B * y.z) * inv;
        c.w = (A * c.w + B * y.w) * inv;
        c2 = wave_reduce_sum(c.x * c.x + c.y * c.y + c.z * c.z + c.w * c.w);
    }

    // rst *= norm
    c.x *= scale; c.y *= scale; c.z *= scale; c.w *= scale;
    c2 *= scale * scale;

    // mobius_add(rst, bias)
    float4 b = *(const float4*)&bias[lane * 4];
    float bbp = b.x * b.x + b.y * b.y + b.z * b.z + b.w * b.w;
    float xyp = c.x * b.x + c.y * b.y + c.z * b.z + c.w * b.w;
    float bb = wave_reduce_sum(bbp);
    float xy = wave_reduce_sum(xyp);
    float A = 1.f + 2.f * xy + bb;
    float B = 1.f - c2;
    float den = fmaxf(1.f + 2.f * xy + c2 * bb, EPSF);
    float inv = 1.f / den;
    float4 r4;
    r4.x = (A * c.x + B * b.x) * inv;
    r4.y = (A * c.y + B * b.y) * inv;
    r4.z = (A * c.z + B * b.z) * inv;
    r4.w = (A * c.w + B * b.w) * inv;

    // logmap0
    float rn2 = wave_reduce_sum(r4.x * r4.x + r4.y * r4.y + r4.z * r4.z + r4.w * r4.w);
    float rn  = fmaxf(sqrtf(rn2), EPSF);
    float lf  = artanh_clip(rn) / rn;
    float4 u;
    u.x = fmaxf(r4.x * lf, 0.f);
    u.y = fmaxf(r4.y * lf, 0.f);
    u.z = fmaxf(r4.z * lf, 0.f);
    u.w = fmaxf(r4.w * lf, 0.f);

    // expmap0
    float un2 = wave_reduce_sum(u.x * u.x + u.y * u.y + u.z * u.z + u.w * u.w);
    float un  = fmaxf(sqrtf(un2), EPSF);
    float ef  = tanhf(un) / un;

    float4 o;
    o.x = u.x * ef; o.y = u.y * ef; o.z = u.z * ef; o.w = u.w * ef;
    *(float4*)&out[(size_t)n * NOUT + lane * 4] = o;
}

extern "C" void kernel_launch(void* const* d_in, const int* in_sizes, int n_in,
                              void* d_out, int out_size, void* d_ws, size_t ws_size,
                              hipStream_t stream) {
    const float* feat   = (const float*)d_in[0];
    const float* weight = (const float*)d_in[1];
    const float* bias   = (const float*)d_in[2];
    const int*   src    = (const int*)d_in[3];

    const int OUT = in_sizes[2];            // 256
    const int IN  = in_sizes[1] / OUT;      // 512
    const int N   = in_sizes[0] / IN;       // 20000
    const int DEG = in_sizes[3] / N;        // 16
    (void)IN; (void)out_size; (void)ws_size; (void)n_in;

    const float scale = 1.0f / sqrtf((float)DEG);  // deg^-0.5 = 0.25

    float* h      = (float*)d_ws;                               // N*OUT floats
    float* hnorm2 = (float*)((char*)d_ws + (size_t)N * OUT * 4); // N floats

    float* out = (float*)d_out;

    int grid1 = (N + TM - 1) / TM;          // 1250
    hipLaunchKernelGGL(matvec_mobius_kernel, dim3(grid1), dim3(256), 0, stream,
                       feat, weight, h, hnorm2, scale, N);

    int grid2 = (N + 3) / 4;                // 5000 (one wave per row)
    hipLaunchKernelGGL(aggregate_kernel, dim3(grid2), dim3(256), 0, stream,
                       h, hnorm2, src, bias, out, scale, N, DEG);
}

// Round 2
// 101.808 us; speedup vs baseline: 1.7497x; 1.7497x over previous
//
#include <hip/hip_runtime.h>
#include <math.h>

#define EPSF 1e-15f
#define MAX_TANH_F (1.0f - 1e-5f)
#define KDIM 512
#define NOUT 256

typedef __attribute__((ext_vector_type(8))) __bf16 bf16x8;
typedef __attribute__((ext_vector_type(4))) float f32x4;

__device__ __forceinline__ unsigned int f2bf(float f) {
    unsigned int u = __float_as_uint(f);
    return (u + 0x7FFFu + ((u >> 16) & 1u)) >> 16;   // RNE, values are tame (no NaN/Inf)
}
__device__ __forceinline__ unsigned int pack2(float lo, float hi) {
    return f2bf(lo) | (f2bf(hi) << 16);
}

__device__ __forceinline__ float wave_reduce_sum(float v) {
    v += __shfl_xor(v, 32);
    v += __shfl_xor(v, 16);
    v += __shfl_xor(v, 8);
    v += __shfl_xor(v, 4);
    v += __shfl_xor(v, 2);
    v += __shfl_xor(v, 1);
    return v;
}

__device__ __forceinline__ float artanh_clip(float x) {
    x = fminf(fmaxf(x, -MAX_TANH_F), MAX_TANH_F);
    return atanhf(x);
}

// P1: featp[rt][s][lane][8] bf16 fragment layout (A-frag: row=lane&15, k=s*32+(lane>>4)*8+j)
// plus exact f32 xn2[row] = ||feat_row * scale||^2.
__global__ __launch_bounds__(256) void prep_feat_kernel(
    const float* __restrict__ feat, unsigned int* __restrict__ featp,
    float* __restrict__ xn2, float scale, int N)
{
    __shared__ float red[4][16];
    const int rt = blockIdx.x;
    const int t = threadIdx.x;
    const int l = t & 63;                       // == chunk&63 for all 4 chunks
    const int row = rt * 16 + (l & 15);
    float xs = 0.f;
    #pragma unroll
    for (int i = 0; i < 4; ++i) {
        const int c = t + 256 * i;              // chunk index within rt-block
        const int s = c >> 6;
        const int k0 = s * 32 + ((l >> 4) & 3) * 8;
        float4 v0 = make_float4(0.f, 0.f, 0.f, 0.f), v1 = v0;
        if (row < N) {
            const float4* fr = (const float4*)(feat + (size_t)row * KDIM + k0);
            v0 = fr[0]; v1 = fr[1];
        }
        v0.x *= scale; v0.y *= scale; v0.z *= scale; v0.w *= scale;
        v1.x *= scale; v1.y *= scale; v1.z *= scale; v1.w *= scale;
        xs += v0.x*v0.x + v0.y*v0.y + v0.z*v0.z + v0.w*v0.w
            + v1.x*v1.x + v1.y*v1.y + v1.z*v1.z + v1.w*v1.w;
        uint4 o;
        o.x = pack2(v0.x, v0.y); o.y = pack2(v0.z, v0.w);
        o.z = pack2(v1.x, v1.y); o.w = pack2(v1.z, v1.w);
        *(uint4*)(featp + ((size_t)rt * 1024 + c) * 4) = o;
    }
    // reduce xs across lanes with same (lane&15), then across the 4 waves
    xs += __shfl_xor(xs, 16);
    xs += __shfl_xor(xs, 32);
    const int wv = t >> 6;
    if (l < 16) red[wv][l] = xs;
    __syncthreads();
    if (t < 16) {
        const int r2 = rt * 16 + t;
        if (r2 < N) xn2[r2] = red[0][t] + red[1][t] + red[2][t] + red[3][t];
    }
}

// P2: Wp[s][nt][lane][8] bf16 fragment layout (B-frag: col=nt*16+(lane&15), k=s*32+(lane>>4)*8+j)
__global__ __launch_bounds__(64) void prep_w_kernel(
    const float* __restrict__ W, unsigned int* __restrict__ Wp)
{
    const int b = blockIdx.x;       // b = s*16 + nt, 256 blocks
    const int l = threadIdx.x;      // 64 lanes
    const int k0 = (b >> 4) * 32 + (l >> 4) * 8;
    const int col = (b & 15) * 16 + (l & 15);
    float f[8];
    #pragma unroll
    for (int j = 0; j < 8; ++j) f[j] = W[(size_t)(k0 + j) * NOUT + col];
    uint4 o;
    o.x = pack2(f[0], f[1]); o.y = pack2(f[2], f[3]);
    o.z = pack2(f[4], f[5]); o.w = pack2(f[6], f[7]);
    *(uint4*)(Wp + ((size_t)b * 64 + l) * 4) = o;
}

// K1': barrier-free MFMA GEMM + mobius rescale. Wave = 16 rows x 256 cols.
__global__ __launch_bounds__(256) void gemm_mobius_kernel(
    const uint4* __restrict__ featp, const uint4* __restrict__ Wp,
    const float* __restrict__ xn2,
    float* __restrict__ h, float* __restrict__ hnorm2, int N)
{
    const int wave = threadIdx.x >> 6;
    const int lane = threadIdx.x & 63;
    const int rt = blockIdx.x * 4 + wave;
    const int base = rt * 16;
    if (base >= N) return;

    f32x4 acc[16];
    #pragma unroll
    for (int t = 0; t < 16; ++t) acc[t] = (f32x4){0.f, 0.f, 0.f, 0.f};

    const uint4* fp = featp + (size_t)rt * (16 * 64) + lane;
    const uint4* wp = Wp + lane;

    for (int s = 0; s < 16; ++s) {
        bf16x8 a = __builtin_bit_cast(bf16x8, fp[s * 64]);
        #pragma unroll
        for (int t = 0; t < 16; ++t) {
            bf16x8 b = __builtin_bit_cast(bf16x8, wp[(s * 16 + t) * 64]);
            acc[t] = __builtin_amdgcn_mfma_f32_16x16x32_bf16(a, b, acc[t], 0, 0, 0);
        }
    }

    const float xv = xn2[base + (lane & 15)];
    const int g = lane >> 4;

    #pragma unroll
    for (int r = 0; r < 4; ++r) {
        // ||mx||^2 for row base + g*4 + r : reduce over the 16-lane column group
        float p = 0.f;
        #pragma unroll
        for (int t = 0; t < 16; ++t) p += acc[t][r] * acc[t][r];
        p += __shfl_xor(p, 1);
        p += __shfl_xor(p, 2);
        p += __shfl_xor(p, 4);
        p += __shfl_xor(p, 8);
        const float xnr = __shfl(xv, g * 4 + r);
        const float mxn = fmaxf(sqrtf(p), EPSF);
        const float xn  = fmaxf(sqrtf(xnr), EPSF);
        float ttv = tanhf(mxn / xn * artanh_clip(xn));
        float fc  = ttv / mxn;
        if (mxn <= 1e-10f) { fc = 0.f; ttv = 0.f; }
        const int row = base + g * 4 + r;
        if (row < N) {
            if ((lane & 15) == 0) hnorm2[row] = ttv * ttv;
            float* hr = h + (size_t)row * NOUT + (lane & 15);
            #pragma unroll
            for (int t = 0; t < 16; ++t) hr[t * 16] = acc[t][r] * fc;
        }
    }
}

// K2: sequential mobius scan; all 16 gathered rows preloaded to registers;
// running norm^2 via closed form (single shuffle-reduce per step).
__global__ __launch_bounds__(256) void aggregate_kernel(
    const float* __restrict__ h, const float* __restrict__ hnorm2,
    const int* __restrict__ src, const float* __restrict__ bias,
    float* __restrict__ out, float scale, int N)
{
    const int wave = threadIdx.x >> 6;
    const int lane = threadIdx.x & 63;
    const int n = blockIdx.x * 4 + wave;
    if (n >= N) return;
    const int* sp = src + (size_t)n * 16;

    int idx[16];
    #pragma unroll
    for (int j = 0; j < 16; ++j) idx[j] = sp[j];

    float4 y[16];
    float  y2[16];
    #pragma unroll
    for (int j = 0; j < 16; ++j) {
        y[j]  = *(const float4*)(h + (size_t)idx[j] * NOUT + lane * 4);
        y2[j] = hnorm2[idx[j]];
    }

    float4 c = y[0];
    float  c2 = y2[0];
    #pragma unroll
    for (int j = 1; j < 16; ++j) {
        const float xy = wave_reduce_sum(c.x*y[j].x + c.y*y[j].y + c.z*y[j].z + c.w*y[j].w);
        const float A = 1.f + 2.f*xy + y2[j];
        const float B = 1.f - c2;
        const float den = fmaxf(1.f + 2.f*xy + c2*y2[j], EPSF);
        const float inv = 1.f / den;
        c.x = (A*c.x + B*y[j].x) * inv;
        c.y = (A*c.y + B*y[j].y) * inv;
        c.z = (A*c.z + B*y[j].z) * inv;
        c.w = (A*c.w + B*y[j].w) * inv;
        c2 = fmaxf((A*A*c2 + 2.f*A*B*xy + B*B*y2[j]) * (inv*inv), 0.f);
    }

    // rst *= norm
    c.x *= scale; c.y *= scale; c.z *= scale; c.w *= scale;
    c2 *= scale * scale;

    // mobius_add(rst, bias)
    const float4 b4 = *(const float4*)(bias + lane * 4);
    const float bb = wave_reduce_sum(b4.x*b4.x + b4.y*b4.y + b4.z*b4.z + b4.w*b4.w);
    const float xy = wave_reduce_sum(c.x*b4.x + c.y*b4.y + c.z*b4.z + c.w*b4.w);
    const float A = 1.f + 2.f*xy + bb;
    const float B = 1.f - c2;
    const float den = fmaxf(1.f + 2.f*xy + c2*bb, EPSF);
    const float inv = 1.f / den;
    float4 r4;
    r4.x = (A*c.x + B*b4.x) * inv;
    r4.y = (A*c.y + B*b4.y) * inv;
    r4.z = (A*c.z + B*b4.z) * inv;
    r4.w = (A*c.w + B*b4.w) * inv;
    const float rn2 = fmaxf((A*A*c2 + 2.f*A*B*xy + B*B*bb) * (inv*inv), 0.f);

    // expmap0(relu(logmap0(r4)))
    const float rn = fmaxf(sqrtf(rn2), EPSF);
    const float lf = artanh_clip(rn) / rn;
    float4 u;
    u.x = fmaxf(r4.x * lf, 0.f);
    u.y = fmaxf(r4.y * lf, 0.f);
    u.z = fmaxf(r4.z * lf, 0.f);
    u.w = fmaxf(r4.w * lf, 0.f);
    const float un2 = wave_reduce_sum(u.x*u.x + u.y*u.y + u.z*u.z + u.w*u.w);
    const float un = fmaxf(sqrtf(un2), EPSF);
    const float ef = tanhf(un) / un;

    float4 o;
    o.x = u.x * ef; o.y = u.y * ef; o.z = u.z * ef; o.w = u.w * ef;
    *(float4*)(out + (size_t)n * NOUT + lane * 4) = o;
}

extern "C" void kernel_launch(void* const* d_in, const int* in_sizes, int n_in,
                              void* d_out, int out_size, void* d_ws, size_t ws_size,
                              hipStream_t stream) {
    const float* feat   = (const float*)d_in[0];
    const float* weight = (const float*)d_in[1];
    const float* bias   = (const float*)d_in[2];
    const int*   src    = (const int*)d_in[3];

    const int OUT = in_sizes[2];            // 256
    const int IN  = in_sizes[1] / OUT;      // 512
    const int N   = in_sizes[0] / IN;       // 20000
    const int DEG = in_sizes[3] / N;        // 16
    (void)IN; (void)DEG; (void)out_size; (void)ws_size; (void)n_in;

    const float scale = 1.0f / sqrtf((float)DEG);

    // ws layout: h (N*256 f32) | hnorm2 (N f32) | xn2 (N f32) | Wp (256 KB)
    char* ws = (char*)d_ws;
    float* h      = (float*)ws;
    float* hnorm2 = (float*)(ws + (size_t)N * NOUT * 4);
    float* xn2    = (float*)(ws + (size_t)N * NOUT * 4 + (size_t)N * 4);
    unsigned int* Wp = (unsigned int*)(ws + (size_t)N * NOUT * 4 + 2 * (size_t)N * 4);

    // featp lives in d_out (exactly N*1024 bytes when 16|N); it is fully consumed
    // by gemm_mobius_kernel before aggregate_kernel overwrites d_out with results.
    unsigned int* featp = (unsigned int*)d_out;
    float* out = (float*)d_out;

    const int nrt = (N + 15) / 16;          // 1250

    hipLaunchKernelGGL(prep_feat_kernel, dim3(nrt), dim3(256), 0, stream,
                       feat, featp, xn2, scale, N);
    hipLaunchKernelGGL(prep_w_kernel, dim3(256), dim3(64), 0, stream,
                       weight, Wp);
    hipLaunchKernelGGL(gemm_mobius_kernel, dim3((nrt + 3) / 4), dim3(256), 0, stream,
                       (const uint4*)featp, (const uint4*)Wp, xn2, h, hnorm2, N);
    hipLaunchKernelGGL(aggregate_kernel, dim3((N + 3) / 4), dim3(256), 0, stream,
                       h, hnorm2, src, bias, out, scale, N);
}

// Round 3
// 66.451 us; speedup vs baseline: 2.6806x; 1.5321x over previous
//
#include <hip/hip_runtime.h>
#include <hip/hip_fp16.h>
#include <math.h>

#define EPSF 1e-15f
#define MAX_TANH_F (1.0f - 1e-5f)
#define KDIM 512
#define NOUT 256

typedef __attribute__((ext_vector_type(8))) __bf16 bf16x8;
typedef __attribute__((ext_vector_type(4))) float f32x4;

__device__ __forceinline__ float artanh_clip(float x) {
    x = fminf(fmaxf(x, -MAX_TANH_F), MAX_TANH_F);
    return atanhf(x);
}

__device__ __forceinline__ void unpack2h(unsigned int u, float& a, float& b) {
    __half2 h = __builtin_bit_cast(__half2, u);
    a = __low2float(h);
    b = __high2float(h);
}

// P2: Wp[s][nt][lane][8] bf16 B-fragment layout (col=nt*16+(lane&15), k=s*32+(lane>>4)*8+j)
__global__ __launch_bounds__(64) void prep_w_kernel(
    const float* __restrict__ W, unsigned int* __restrict__ Wp)
{
    const int b = blockIdx.x;       // b = s*16 + nt, 256 blocks
    const int l = threadIdx.x;      // 64 lanes
    const int k0 = (b >> 4) * 32 + (l >> 4) * 8;
    const int col = (b & 15) * 16 + (l & 15);
    bf16x8 v;
    #pragma unroll
    for (int j = 0; j < 8; ++j) v[j] = (__bf16)W[(size_t)(k0 + j) * NOUT + col];
    *(uint4*)(Wp + ((size_t)b * 64 + l) * 4) = __builtin_bit_cast(uint4, v);
}

// K1: fused prep+GEMM+mobius_matvec. Wave = 16 rows x 256 cols, barrier-free.
// Reads f32 feat directly in A-fragment pattern, cvt bf16 in-register,
// exact f32 row norms in-register. Writes h as fp16 + hnorm2 f32.
__global__ __launch_bounds__(256) void gemm_mobius_kernel(
    const float* __restrict__ feat, const uint4* __restrict__ Wp,
    __half* __restrict__ h, float* __restrict__ hnorm2,
    float scale, int N, int nrt)
{
    const int wave = threadIdx.x >> 6;
    const int lane = threadIdx.x & 63;
    const int rt = blockIdx.x * 4 + wave;
    if (rt >= nrt) return;
    const int base = rt * 16;

    f32x4 acc[16];
    #pragma unroll
    for (int t = 0; t < 16; ++t) acc[t] = (f32x4){0.f, 0.f, 0.f, 0.f};

    const int r15 = lane & 15;
    const int g   = lane >> 4;
    const int row = base + r15;
    const int rowc = row < N ? row : (N - 1);
    const float* fr = feat + (size_t)rowc * KDIM + g * 8;
    const uint4* wp = Wp + lane;

    float xs = 0.f;
    for (int s = 0; s < 16; ++s) {
        const float4* f4p = (const float4*)(fr + s * 32);
        float4 v0 = f4p[0];
        float4 v1 = f4p[1];
        v0.x *= scale; v0.y *= scale; v0.z *= scale; v0.w *= scale;
        v1.x *= scale; v1.y *= scale; v1.z *= scale; v1.w *= scale;
        xs += v0.x*v0.x + v0.y*v0.y + v0.z*v0.z + v0.w*v0.w
            + v1.x*v1.x + v1.y*v1.y + v1.z*v1.z + v1.w*v1.w;
        bf16x8 a;
        a[0] = (__bf16)v0.x; a[1] = (__bf16)v0.y; a[2] = (__bf16)v0.z; a[3] = (__bf16)v0.w;
        a[4] = (__bf16)v1.x; a[5] = (__bf16)v1.y; a[6] = (__bf16)v1.z; a[7] = (__bf16)v1.w;
        #pragma unroll
        for (int t = 0; t < 16; ++t) {
            bf16x8 b = __builtin_bit_cast(bf16x8, wp[(s * 16 + t) * 64]);
            acc[t] = __builtin_amdgcn_mfma_f32_16x16x32_bf16(a, b, acc[t], 0, 0, 0);
        }
    }
    // xs: partial over k-quarter g for row base+r15 -> reduce across quarters
    xs += __shfl_xor(xs, 16);
    xs += __shfl_xor(xs, 32);

    #pragma unroll
    for (int r = 0; r < 4; ++r) {
        float p = 0.f;
        #pragma unroll
        for (int t = 0; t < 16; ++t) p += acc[t][r] * acc[t][r];
        p += __shfl_xor(p, 1);
        p += __shfl_xor(p, 2);
        p += __shfl_xor(p, 4);
        p += __shfl_xor(p, 8);
        const float xnr = __shfl(xs, g * 4 + r);
        const float mxn = fmaxf(sqrtf(p), EPSF);
        const float xn  = fmaxf(sqrtf(xnr), EPSF);
        float ttv = tanhf(mxn / xn * artanh_clip(xn));
        float fc  = ttv / mxn;
        if (mxn <= 1e-10f) { fc = 0.f; ttv = 0.f; }
        const int row_r = base + g * 4 + r;
        if (row_r < N) {
            if (r15 == 0) hnorm2[row_r] = ttv * ttv;
            __half* hr = h + (size_t)row_r * NOUT + r15;
            #pragma unroll
            for (int t = 0; t < 16; ++t) hr[t * 16] = __float2half(acc[t][r] * fc);
        }
    }
}

// K2: sequential mobius scan. 16 lanes per row (each lane owns 16 comps),
// 4 rows per wave; one 4-shuffle reduce per step shared by 4 rows; fp16 h.
__global__ __launch_bounds__(256) void aggregate_kernel(
    const __half* __restrict__ h, const float* __restrict__ hnorm2,
    const int* __restrict__ src, const float* __restrict__ bias,
    float* __restrict__ out, float scale, int N)
{
    const int wave = threadIdx.x >> 6;
    const int lane = threadIdx.x & 63;
    const int n0 = (blockIdx.x * 4 + wave) * 4;   // first of this wave's 4 rows
    if (n0 >= N) return;
    const int g = lane >> 4;      // row slot
    const int q = lane & 15;      // component group: comps q*16 .. q*16+15
    const int myrow = n0 + g;
    const bool rowok = myrow < N;

    // 64 src ints for the 4 rows, then per-group broadcast
    size_t smax = (size_t)N * 16 - 1;
    size_t soff = (size_t)n0 * 16 + lane;
    int sidx = src[soff <= smax ? soff : smax];
    int idx[16];
    #pragma unroll
    for (int j = 0; j < 16; ++j) idx[j] = __shfl(sidx, (lane & 48) + j);

    float y2[16];
    #pragma unroll
    for (int j = 0; j < 16; ++j) y2[j] = hnorm2[idx[j]];

    // c init from j=0
    uint4 cur0, cur1, nxt0, nxt1;
    {
        const uint4* hp = (const uint4*)(h + (size_t)idx[0] * NOUT);
        cur0 = hp[q * 2]; cur1 = hp[q * 2 + 1];
        const uint4* hp1 = (const uint4*)(h + (size_t)idx[1] * NOUT);
        nxt0 = hp1[q * 2]; nxt1 = hp1[q * 2 + 1];
    }
    float c[16];
    unpack2h(cur0.x, c[0], c[1]);   unpack2h(cur0.y, c[2], c[3]);
    unpack2h(cur0.z, c[4], c[5]);   unpack2h(cur0.w, c[6], c[7]);
    unpack2h(cur1.x, c[8], c[9]);   unpack2h(cur1.y, c[10], c[11]);
    unpack2h(cur1.z, c[12], c[13]); unpack2h(cur1.w, c[14], c[15]);
    float c2 = y2[0];

    #pragma unroll
    for (int j = 1; j < 16; ++j) {
        uint4 p0 = nxt0, p1 = nxt1;
        if (j + 1 < 16) {
            const uint4* hp = (const uint4*)(h + (size_t)idx[j + 1] * NOUT);
            nxt0 = hp[q * 2]; nxt1 = hp[q * 2 + 1];
        }
        float yv[16];
        unpack2h(p0.x, yv[0], yv[1]);   unpack2h(p0.y, yv[2], yv[3]);
        unpack2h(p0.z, yv[4], yv[5]);   unpack2h(p0.w, yv[6], yv[7]);
        unpack2h(p1.x, yv[8], yv[9]);   unpack2h(p1.y, yv[10], yv[11]);
        unpack2h(p1.z, yv[12], yv[13]); unpack2h(p1.w, yv[14], yv[15]);

        float xp = 0.f;
        #pragma unroll
        for (int i = 0; i < 16; ++i) xp = fmaf(c[i], yv[i], xp);
        xp += __shfl_xor(xp, 1);
        xp += __shfl_xor(xp, 2);
        xp += __shfl_xor(xp, 4);
        xp += __shfl_xor(xp, 8);
        const float xy = xp;

        const float A = 1.f + 2.f * xy + y2[j];
        const float B = 1.f - c2;
        const float den = fmaxf(1.f + 2.f * xy + c2 * y2[j], EPSF);
        const float inv = 1.f / den;
        #pragma unroll
        for (int i = 0; i < 16; ++i) c[i] = (fmaf(A, c[i], B * yv[i])) * inv;
        c2 = fmaxf((A * A * c2 + 2.f * A * B * xy + B * B * y2[j]) * (inv * inv), 0.f);
    }

    // rst *= scale
    #pragma unroll
    for (int i = 0; i < 16; ++i) c[i] *= scale;
    c2 *= scale * scale;

    // mobius_add(rst, bias)
    float bv[16];
    {
        const float4* bp = (const float4*)(bias + q * 16);
        float4 b0 = bp[0], b1 = bp[1], b2 = bp[2], b3 = bp[3];
        bv[0]=b0.x; bv[1]=b0.y; bv[2]=b0.z; bv[3]=b0.w;
        bv[4]=b1.x; bv[5]=b1.y; bv[6]=b1.z; bv[7]=b1.w;
        bv[8]=b2.x; bv[9]=b2.y; bv[10]=b2.z; bv[11]=b2.w;
        bv[12]=b3.x; bv[13]=b3.y; bv[14]=b3.z; bv[15]=b3.w;
    }
    float bp_ = 0.f, xp_ = 0.f;
    #pragma unroll
    for (int i = 0; i < 16; ++i) { bp_ = fmaf(bv[i], bv[i], bp_); xp_ = fmaf(c[i], bv[i], xp_); }
    bp_ += __shfl_xor(bp_, 1); xp_ += __shfl_xor(xp_, 1);
    bp_ += __shfl_xor(bp_, 2); xp_ += __shfl_xor(xp_, 2);
    bp_ += __shfl_xor(bp_, 4); xp_ += __shfl_xor(xp_, 4);
    bp_ += __shfl_xor(bp_, 8); xp_ += __shfl_xor(xp_, 8);
    const float bb = bp_, xy = xp_;

    const float A = 1.f + 2.f * xy + bb;
    const float B = 1.f - c2;
    const float den = fmaxf(1.f + 2.f * xy + c2 * bb, EPSF);
    const float inv = 1.f / den;
    float r4[16];
    #pragma unroll
    for (int i = 0; i < 16; ++i) r4[i] = fmaf(A, c[i], B * bv[i]) * inv;
    const float rn2 = fmaxf((A * A * c2 + 2.f * A * B * xy + B * B * bb) * (inv * inv), 0.f);

    // expmap0(relu(logmap0(.)))
    const float rn = fmaxf(sqrtf(rn2), EPSF);
    const float lf = artanh_clip(rn) / rn;
    float u[16];
    float up = 0.f;
    #pragma unroll
    for (int i = 0; i < 16; ++i) { u[i] = fmaxf(r4[i] * lf, 0.f); up = fmaf(u[i], u[i], up); }
    up += __shfl_xor(up, 1);
    up += __shfl_xor(up, 2);
    up += __shfl_xor(up, 4);
    up += __shfl_xor(up, 8);
    const float un = fmaxf(sqrtf(up), EPSF);
    const float ef = tanhf(un) / un;

    if (rowok) {
        float* op = out + (size_t)myrow * NOUT + q * 16;
        float4 o;
        o.x = u[0]*ef;  o.y = u[1]*ef;  o.z = u[2]*ef;  o.w = u[3]*ef;  ((float4*)op)[0] = o;
        o.x = u[4]*ef;  o.y = u[5]*ef;  o.z = u[6]*ef;  o.w = u[7]*ef;  ((float4*)op)[1] = o;
        o.x = u[8]*ef;  o.y = u[9]*ef;  o.z = u[10]*ef; o.w = u[11]*ef; ((float4*)op)[2] = o;
        o.x = u[12]*ef; o.y = u[13]*ef; o.z = u[14]*ef; o.w = u[15]*ef; ((float4*)op)[3] = o;
    }
}

extern "C" void kernel_launch(void* const* d_in, const int* in_sizes, int n_in,
                              void* d_out, int out_size, void* d_ws, size_t ws_size,
                              hipStream_t stream) {
    const float* feat   = (const float*)d_in[0];
    const float* weight = (const float*)d_in[1];
    const float* bias   = (const float*)d_in[2];
    const int*   src    = (const int*)d_in[3];

    const int OUT = in_sizes[2];            // 256
    const int IN  = in_sizes[1] / OUT;      // 512
    const int N   = in_sizes[0] / IN;       // 20000
    const int DEG = in_sizes[3] / N;        // 16
    (void)IN; (void)DEG; (void)out_size; (void)ws_size; (void)n_in;

    const float scale = 1.0f / sqrtf((float)DEG);

    // ws layout: h fp16 (N*256*2 B) | hnorm2 (N f32) | Wp (256 KB)
    char* ws = (char*)d_ws;
    __half* h     = (__half*)ws;
    float* hnorm2 = (float*)(ws + (size_t)N * NOUT * 2);
    unsigned int* Wp = (unsigned int*)(ws + (size_t)N * NOUT * 2 + (size_t)N * 4);

    float* out = (float*)d_out;

    const int nrt = (N + 15) / 16;          // 1250

    hipLaunchKernelGGL(prep_w_kernel, dim3(256), dim3(64), 0, stream,
                       weight, Wp);
    hipLaunchKernelGGL(gemm_mobius_kernel, dim3((nrt + 3) / 4), dim3(256), 0, stream,
                       feat, (const uint4*)Wp, h, hnorm2, scale, N, nrt);
    hipLaunchKernelGGL(aggregate_kernel, dim3((N + 15) / 16), dim3(256), 0, stream,
                       h, hnorm2, src, bias, out, scale, N);
}